// Round 12
// baseline (67.197 us; speedup 1.0000x reference)
//
#include <hip/hip_runtime.h>

// Voxelizer3D: out[f][z][y][x] = sum over masked atoms (all coords != 0) whose
// center cell is within Chebyshev distance 1 of (x,y,z), of feat[a][f].
// v12: r11 pipeline with accum widened to 16 cells/block (4 waves x 4 cells
// sequential) -> center writes become 64B-contiguous (19 write transactions
// per block instead of 76). minmax/scatter/conv2 unchanged.

constexpr int VOL   = 48;
constexpr int FEATD = 19;
constexpr int VOL3  = VOL * VOL * VOL;      // 110592
constexpr int CAP   = 128;                  // bucket capacity per cell
constexpr int OVCAP = 8192;                 // overflow list capacity (cold)
constexpr int NMB   = 64;                   // minmax partial blocks
constexpr int SCB   = 256;
constexpr int CPB16 = 16;                   // accum cells per block
constexpr int NAB   = VOL3 / CPB16;         // 6912 accum blocks

__device__ __forceinline__ unsigned fkey(float f) {
    unsigned u = __float_as_uint(f);
    return (u & 0x80000000u) ? ~u : (u | 0x80000000u);
}
__device__ __forceinline__ float funkey(unsigned k) {
    unsigned u = (k & 0x80000000u) ? (k & 0x7fffffffu) : ~k;
    return __uint_as_float(u);
}

// ---- K1: per-block min/max partials; zero counts + ovf counter ----
__global__ __launch_bounds__(1024) void vox_minmax_p(const float* __restrict__ xyz,
                                                     int n, unsigned* __restrict__ pb,
                                                     unsigned* __restrict__ counts,
                                                     unsigned* __restrict__ ovf_cnt) {
    int gid = blockIdx.x * blockDim.x + threadIdx.x;
    for (int j = gid; j < VOL3; j += gridDim.x * blockDim.x) counts[j] = 0u;
    if (gid == 0) *ovf_cnt = 0u;
    __shared__ unsigned smin[16][3], smax[16][3];
    unsigned kmin[3] = {~0u, ~0u, ~0u};
    unsigned kmax[3] = {0u, 0u, 0u};
    const int nq = n >> 2;
    const float4* p4 = (const float4*)xyz;
    for (int q = gid; q < nq; q += gridDim.x * blockDim.x) {
        float4 v0 = p4[3 * q], v1 = p4[3 * q + 1], v2 = p4[3 * q + 2];
        float ax[4] = {v0.x, v0.w, v1.z, v2.y};
        float ay[4] = {v0.y, v1.x, v1.w, v2.z};
        float az[4] = {v0.z, v1.y, v2.x, v2.w};
        #pragma unroll
        for (int k = 0; k < 4; k++) {
            if (ax[k] != 0.f && ay[k] != 0.f && az[k] != 0.f) {
                unsigned kk[3] = {fkey(ax[k]), fkey(ay[k]), fkey(az[k])};
                #pragma unroll
                for (int c = 0; c < 3; c++) {
                    kmin[c] = kmin[c] < kk[c] ? kmin[c] : kk[c];
                    kmax[c] = kmax[c] > kk[c] ? kmax[c] : kk[c];
                }
            }
        }
    }
    for (int i = (nq << 2) + gid; i < n; i += gridDim.x * blockDim.x) {
        float x = xyz[3 * i], y = xyz[3 * i + 1], z = xyz[3 * i + 2];
        if (x != 0.f && y != 0.f && z != 0.f) {
            unsigned kk[3] = {fkey(x), fkey(y), fkey(z)};
            #pragma unroll
            for (int c = 0; c < 3; c++) {
                kmin[c] = kmin[c] < kk[c] ? kmin[c] : kk[c];
                kmax[c] = kmax[c] > kk[c] ? kmax[c] : kk[c];
            }
        }
    }
    #pragma unroll
    for (int o = 32; o; o >>= 1) {
        #pragma unroll
        for (int c = 0; c < 3; c++) {
            unsigned omin = __shfl_xor(kmin[c], o, 64);
            unsigned omax = __shfl_xor(kmax[c], o, 64);
            kmin[c] = kmin[c] < omin ? kmin[c] : omin;
            kmax[c] = kmax[c] > omax ? kmax[c] : omax;
        }
    }
    int wave = threadIdx.x >> 6;
    if ((threadIdx.x & 63) == 0) {
        #pragma unroll
        for (int c = 0; c < 3; c++) { smin[wave][c] = kmin[c]; smax[wave][c] = kmax[c]; }
    }
    __syncthreads();
    if (threadIdx.x == 0) {
        int nw = blockDim.x >> 6;
        #pragma unroll
        for (int c = 0; c < 3; c++) { kmin[c] = smin[0][c]; kmax[c] = smax[0][c]; }
        for (int w = 1; w < nw; w++) {
            #pragma unroll
            for (int c = 0; c < 3; c++) {
                kmin[c] = kmin[c] < smin[w][c] ? kmin[c] : smin[w][c];
                kmax[c] = kmax[c] > smax[w][c] ? kmax[c] : smax[w][c];
            }
        }
        #pragma unroll
        for (int c = 0; c < 3; c++) {
            pb[blockIdx.x * 6 + c]     = kmin[c];
            pb[blockIdx.x * 6 + 3 + c] = kmax[c];
        }
    }
}

// reduce the NMB partials -> 6 floats, broadcast via LDS
__device__ __forceinline__ void reduce_keys64(const unsigned* __restrict__ pb,
                                              float* __restrict__ sm) {
    if (threadIdx.x < 64) {
        unsigned mn[3], mx[3];
        int t = threadIdx.x;
        #pragma unroll
        for (int c = 0; c < 3; c++) {
            mn[c] = pb[t * 6 + c];
            mx[c] = pb[t * 6 + 3 + c];
        }
        #pragma unroll
        for (int o = 32; o; o >>= 1) {
            #pragma unroll
            for (int c = 0; c < 3; c++) {
                unsigned omin = __shfl_xor(mn[c], o, 64);
                unsigned omax = __shfl_xor(mx[c], o, 64);
                mn[c] = mn[c] < omin ? mn[c] : omin;
                mx[c] = mx[c] > omax ? mx[c] : omax;
            }
        }
        if (t == 0) {
            #pragma unroll
            for (int c = 0; c < 3; c++) { sm[c] = funkey(mn[c]); sm[3 + c] = funkey(mx[c]); }
        }
    }
    __syncthreads();
}

// ---- K2: fused cell-compute + count + bucket-place (4 atoms/thread) ----
__global__ __launch_bounds__(SCB) void vox_scatter(const float* __restrict__ xyz, int n,
                                                   const unsigned* __restrict__ pb,
                                                   unsigned* __restrict__ counts,
                                                   unsigned* __restrict__ bucket,
                                                   unsigned* __restrict__ ovf,
                                                   unsigned* __restrict__ ovf_cnt) {
    __shared__ float sm[6];
    reduce_keys64(pb, sm);
    const float mnx = sm[0], mny = sm[1], mnz = sm[2];
    const float mxx = sm[3], mxy = sm[4], mxz = sm[5];
    int q = blockIdx.x * blockDim.x + threadIdx.x;
    int i0 = q * 4;
    if (i0 >= n) return;
    float ax[4], ay[4], az[4];
    int cnt4 = 4;
    if (i0 + 4 <= n) {
        const float4* p4 = (const float4*)(xyz + (size_t)i0 * 3);
        float4 v0 = p4[0], v1 = p4[1], v2 = p4[2];
        ax[0]=v0.x; ax[1]=v0.w; ax[2]=v1.z; ax[3]=v2.y;
        ay[0]=v0.y; ay[1]=v1.x; ay[2]=v1.w; ay[3]=v2.z;
        az[0]=v0.z; az[1]=v1.y; az[2]=v2.x; az[3]=v2.w;
    } else {
        cnt4 = n - i0;
        for (int k = 0; k < cnt4; k++) {
            ax[k] = xyz[3 * (i0 + k)]; ay[k] = xyz[3 * (i0 + k) + 1]; az[k] = xyz[3 * (i0 + k) + 2];
        }
    }
    #pragma unroll
    for (int k = 0; k < 4; k++) {
        if (k >= cnt4) break;
        if (ax[k] == 0.f || ay[k] == 0.f || az[k] == 0.f) continue;
        // exact op-order of reference: (x - min) / (max - min) * 47, f32, trunc
        int cx = (int)((ax[k] - mnx) / (mxx - mnx) * 47.0f);
        int cy = (int)((ay[k] - mny) / (mxy - mny) * 47.0f);
        int cz = (int)((az[k] - mnz) / (mxz - mnz) * 47.0f);
        unsigned cell = (unsigned)((cz * VOL + cy) * VOL + cx);
        unsigned slot = atomicAdd(&counts[cell], 1u);
        if (slot < CAP) {
            bucket[(size_t)cell * CAP + slot] = (unsigned)(i0 + k);
        } else {
            unsigned j = atomicAdd(ovf_cnt, 1u);
            if (j < OVCAP) { ovf[2 * j] = cell; ovf[2 * j + 1] = (unsigned)(i0 + k); }
        }
    }
}

// ---- K3: accum; 16 cells/block (wave w -> cells w,4+w,8+w,12+w) ----
__global__ __launch_bounds__(256) void vox_accum16(const unsigned* __restrict__ bucket,
                                                   const unsigned* __restrict__ counts,
                                                   const unsigned* __restrict__ ovf,
                                                   const unsigned* __restrict__ ovf_cnt,
                                                   const float* __restrict__ feat,
                                                   float* __restrict__ center) {
    __shared__ float tile[CPB16][FEATD];
    const int wave = threadIdx.x >> 6;
    const int lane = threadIdx.x & 63;
    const int base = blockIdx.x * CPB16;            // grid.x = VOL3/16
    const int f = lane % FEATD;                     // 0..18
    const int j = lane / FEATD;                     // 0..3 (j==3: idle lanes)
    const bool act = j < 3;

    #pragma unroll
    for (int cc = 0; cc < 4; cc++) {
        const int ci = cc * 4 + wave;               // 0..15, wave-strided
        const int cell = base + ci;
        unsigned cnt = counts[cell];
        unsigned use = cnt < CAP ? cnt : CAP;
        const unsigned* b = bucket + (size_t)cell * CAP;
        float acc = 0.f;
        // software-pipelined: 6 atoms/round (2 per j-group), indices one round ahead
        unsigned idx0 = 0, idx1 = 0;
        bool l0 = act && ((unsigned)j < use);
        bool l1 = act && ((unsigned)(j + 3) < use);
        if (l0) idx0 = b[j];
        if (l1) idx1 = b[j + 3];
        unsigned k = 0;
        while (k < use) {
            unsigned nk = k + 6;
            bool n0 = act && (nk + j < use);
            bool n1 = act && (nk + j + 3 < use);
            unsigned nidx0 = 0, nidx1 = 0;
            if (n0) nidx0 = b[nk + j];
            if (n1) nidx1 = b[nk + j + 3];
            if (l0) acc += feat[(size_t)idx0 * FEATD + f];   // 19 lanes span one row
            if (l1) acc += feat[(size_t)idx1 * FEATD + f];
            k = nk; idx0 = nidx0; idx1 = nidx1; l0 = n0; l1 = n1;
        }
        if (cnt > CAP) {   // cold overflow merge (never taken for this data)
            unsigned no = *ovf_cnt; if (no > OVCAP) no = OVCAP;
            if (lane < FEATD) {
                for (unsigned i = 0; i < no; i++)
                    if (ovf[2 * i] == (unsigned)cell)
                        acc += feat[(size_t)ovf[2 * i + 1] * FEATD + f];
            }
        }
        float a1 = __shfl(acc, lane + FEATD, 64);
        float a2 = __shfl(acc, lane + 2 * FEATD, 64);
        if (lane < FEATD) tile[ci][lane] = acc + a1 + a2;
    }
    __syncthreads();
    // coalesced write: 16 consecutive cells per feature plane = one 64B burst
    for (int t = threadIdx.x; t < CPB16 * FEATD; t += SCB) {
        int ff = t >> 4, c = t & 15;                // t/16, t%16
        center[(size_t)ff * VOL3 + base + c] = tile[c][ff];
    }
}

// ---- K4: 3x3x3 box conv; thread computes a 4x4 (x,z) tile via float4 rows ----
constexpr int XQ = VOL / 4;     // 12 x-quads
constexpr int CZB = VOL / 4;    // 12 z-blocks (4 z per thread)
constexpr int NCONV2 = FEATD * CZB * VOL * XQ;   // 131328 threads

__global__ __launch_bounds__(SCB) void vox_conv2(const float* __restrict__ center,
                                                 float* __restrict__ out) {
    int idx = blockIdx.x * blockDim.x + threadIdx.x;
    if (idx >= NCONV2) return;
    int xq = idx % XQ;
    int t = idx / XQ;
    int y = t % VOL;  t /= VOL;
    int zb = t % CZB;
    int f = t / CZB;
    const int x0 = xq * 4;
    const float* cf = center + (size_t)f * VOL3;

    const int ylo = (y > 0) ? y - 1 : 0, yhi = (y < VOL - 1) ? y + 1 : VOL - 1;

    auto rowsum4 = [&](const float* row) -> float4 {
        float4 a = *(const float4*)(row + x0);
        float m = (x0 > 0) ? row[x0 - 1] : 0.f;
        float p = (x0 + 4 < VOL) ? row[x0 + 4] : 0.f;
        return make_float4(m + a.x + a.y,
                           a.x + a.y + a.z,
                           a.y + a.z + a.w,
                           a.z + a.w + p);
    };
    auto psum = [&](int zz) -> float4 {
        float4 s = make_float4(0.f, 0.f, 0.f, 0.f);
        if ((unsigned)zz >= (unsigned)VOL) return s;
        for (int yy = ylo; yy <= yhi; yy++) {
            float4 r = rowsum4(cf + (zz * VOL + yy) * VOL);
            s.x += r.x; s.y += r.y; s.z += r.z; s.w += r.w;
        }
        return s;
    };

    const int z0 = zb * 4;
    float4 Pm = psum(z0 - 1), Pc = psum(z0);
    #pragma unroll
    for (int k = 0; k < 4; k++) {
        float4 Pn = psum(z0 + k + 1);
        float4 o = make_float4(Pm.x + Pc.x + Pn.x, Pm.y + Pc.y + Pn.y,
                               Pm.z + Pc.z + Pn.z, Pm.w + Pc.w + Pn.w);
        *(float4*)(out + (((size_t)f * VOL + (z0 + k)) * VOL + y) * VOL + x0) = o;
        Pm = Pc; Pc = Pn;
    }
}

extern "C" void kernel_launch(void* const* d_in, const int* in_sizes, int n_in,
                              void* d_out, int out_size, void* d_ws, size_t ws_size,
                              hipStream_t stream) {
    const float* xyz  = (const float*)d_in[0];
    const float* feat = (const float*)d_in[1];
    float* out = (float*)d_out;
    int n = in_sizes[0] / 3;

    char* w = (char*)d_ws;
    unsigned* pb      = (unsigned*)w;                        // NMB*6 u32 = 1536 B
    unsigned* ovf_cnt = (unsigned*)(w + 1536);               // 4 B (pad to 2048)
    unsigned* counts  = (unsigned*)(w + 2048);               // VOL3*4 = 442368
    size_t o3 = 2048 + (size_t)VOL3 * 4;                     // 444416 (256-aligned)
    unsigned* bucket  = (unsigned*)(w + o3);                 // VOL3*CAP*4 = 56.6 MB
    size_t o4 = o3 + (size_t)VOL3 * CAP * 4;
    float* center     = (float*)(w + o4);                    // FEATD*VOL3*4 = 8.4 MB
    size_t o5 = o4 + (size_t)FEATD * VOL3 * 4;
    unsigned* ovf     = (unsigned*)(w + o5);                 // 2*OVCAP*4 = 64 KB
    size_t need = o5 + (size_t)2 * OVCAP * 4;

    if (ws_size < need) return;   // harness ws is ~256MB; never taken

    int nq = (n + 3) / 4;
    vox_minmax_p<<<NMB, 1024, 0, stream>>>(xyz, n, pb, counts, ovf_cnt);
    vox_scatter<<<(nq + SCB - 1) / SCB, SCB, 0, stream>>>(xyz, n, pb, counts, bucket, ovf, ovf_cnt);
    vox_accum16<<<NAB, 256, 0, stream>>>(bucket, counts, ovf, ovf_cnt, feat, center);
    vox_conv2<<<(NCONV2 + SCB - 1) / SCB, SCB, 0, stream>>>(center, out);
}

// Round 13
// 53.038 us; speedup vs baseline: 1.2670x; 1.2670x over previous
//
#include <hip/hip_runtime.h>

// Voxelizer3D: out[f][z][y][x] = sum over masked atoms (all coords != 0) whose
// center cell is within Chebyshev distance 1 of (x,y,z), of feat[a][f].
// v13: r11 pipeline; accum = 512-thread blocks, 8 waves, ONE cell per wave
// (same wave-parallelism as r11 = 110592 waves) with 32B-contiguous writes.
// (v12 lesson: never trade wave-count for write coalescing in latency-bound
// gather kernels — 4 cells/wave sequential cost 4x TLP and 28% total time.)

constexpr int VOL   = 48;
constexpr int FEATD = 19;
constexpr int VOL3  = VOL * VOL * VOL;      // 110592
constexpr int CAP   = 128;                  // bucket capacity per cell
constexpr int OVCAP = 8192;                 // overflow list capacity (cold)
constexpr int NMB   = 64;                   // minmax partial blocks
constexpr int SCB   = 256;
constexpr int ACB   = 512;                  // accum block threads (8 waves)
constexpr int CPB8  = 8;                    // accum cells per block (1 per wave)
constexpr int NAB   = VOL3 / CPB8;          // 13824 accum blocks

__device__ __forceinline__ unsigned fkey(float f) {
    unsigned u = __float_as_uint(f);
    return (u & 0x80000000u) ? ~u : (u | 0x80000000u);
}
__device__ __forceinline__ float funkey(unsigned k) {
    unsigned u = (k & 0x80000000u) ? (k & 0x7fffffffu) : ~k;
    return __uint_as_float(u);
}

// ---- K1: per-block min/max partials; zero counts + ovf counter ----
__global__ __launch_bounds__(1024) void vox_minmax_p(const float* __restrict__ xyz,
                                                     int n, unsigned* __restrict__ pb,
                                                     unsigned* __restrict__ counts,
                                                     unsigned* __restrict__ ovf_cnt) {
    int gid = blockIdx.x * blockDim.x + threadIdx.x;
    for (int j = gid; j < VOL3; j += gridDim.x * blockDim.x) counts[j] = 0u;
    if (gid == 0) *ovf_cnt = 0u;
    __shared__ unsigned smin[16][3], smax[16][3];
    unsigned kmin[3] = {~0u, ~0u, ~0u};
    unsigned kmax[3] = {0u, 0u, 0u};
    const int nq = n >> 2;
    const float4* p4 = (const float4*)xyz;
    for (int q = gid; q < nq; q += gridDim.x * blockDim.x) {
        float4 v0 = p4[3 * q], v1 = p4[3 * q + 1], v2 = p4[3 * q + 2];
        float ax[4] = {v0.x, v0.w, v1.z, v2.y};
        float ay[4] = {v0.y, v1.x, v1.w, v2.z};
        float az[4] = {v0.z, v1.y, v2.x, v2.w};
        #pragma unroll
        for (int k = 0; k < 4; k++) {
            if (ax[k] != 0.f && ay[k] != 0.f && az[k] != 0.f) {
                unsigned kk[3] = {fkey(ax[k]), fkey(ay[k]), fkey(az[k])};
                #pragma unroll
                for (int c = 0; c < 3; c++) {
                    kmin[c] = kmin[c] < kk[c] ? kmin[c] : kk[c];
                    kmax[c] = kmax[c] > kk[c] ? kmax[c] : kk[c];
                }
            }
        }
    }
    for (int i = (nq << 2) + gid; i < n; i += gridDim.x * blockDim.x) {
        float x = xyz[3 * i], y = xyz[3 * i + 1], z = xyz[3 * i + 2];
        if (x != 0.f && y != 0.f && z != 0.f) {
            unsigned kk[3] = {fkey(x), fkey(y), fkey(z)};
            #pragma unroll
            for (int c = 0; c < 3; c++) {
                kmin[c] = kmin[c] < kk[c] ? kmin[c] : kk[c];
                kmax[c] = kmax[c] > kk[c] ? kmax[c] : kk[c];
            }
        }
    }
    #pragma unroll
    for (int o = 32; o; o >>= 1) {
        #pragma unroll
        for (int c = 0; c < 3; c++) {
            unsigned omin = __shfl_xor(kmin[c], o, 64);
            unsigned omax = __shfl_xor(kmax[c], o, 64);
            kmin[c] = kmin[c] < omin ? kmin[c] : omin;
            kmax[c] = kmax[c] > omax ? kmax[c] : omax;
        }
    }
    int wave = threadIdx.x >> 6;
    if ((threadIdx.x & 63) == 0) {
        #pragma unroll
        for (int c = 0; c < 3; c++) { smin[wave][c] = kmin[c]; smax[wave][c] = kmax[c]; }
    }
    __syncthreads();
    if (threadIdx.x == 0) {
        int nw = blockDim.x >> 6;
        #pragma unroll
        for (int c = 0; c < 3; c++) { kmin[c] = smin[0][c]; kmax[c] = smax[0][c]; }
        for (int w = 1; w < nw; w++) {
            #pragma unroll
            for (int c = 0; c < 3; c++) {
                kmin[c] = kmin[c] < smin[w][c] ? kmin[c] : smin[w][c];
                kmax[c] = kmax[c] > smax[w][c] ? kmax[c] : smax[w][c];
            }
        }
        #pragma unroll
        for (int c = 0; c < 3; c++) {
            pb[blockIdx.x * 6 + c]     = kmin[c];
            pb[blockIdx.x * 6 + 3 + c] = kmax[c];
        }
    }
}

// reduce the NMB partials -> 6 floats, broadcast via LDS
__device__ __forceinline__ void reduce_keys64(const unsigned* __restrict__ pb,
                                              float* __restrict__ sm) {
    if (threadIdx.x < 64) {
        unsigned mn[3], mx[3];
        int t = threadIdx.x;
        #pragma unroll
        for (int c = 0; c < 3; c++) {
            mn[c] = pb[t * 6 + c];
            mx[c] = pb[t * 6 + 3 + c];
        }
        #pragma unroll
        for (int o = 32; o; o >>= 1) {
            #pragma unroll
            for (int c = 0; c < 3; c++) {
                unsigned omin = __shfl_xor(mn[c], o, 64);
                unsigned omax = __shfl_xor(mx[c], o, 64);
                mn[c] = mn[c] < omin ? mn[c] : omin;
                mx[c] = mx[c] > omax ? mx[c] : omax;
            }
        }
        if (t == 0) {
            #pragma unroll
            for (int c = 0; c < 3; c++) { sm[c] = funkey(mn[c]); sm[3 + c] = funkey(mx[c]); }
        }
    }
    __syncthreads();
}

// ---- K2: fused cell-compute + count + bucket-place (4 atoms/thread) ----
__global__ __launch_bounds__(SCB) void vox_scatter(const float* __restrict__ xyz, int n,
                                                   const unsigned* __restrict__ pb,
                                                   unsigned* __restrict__ counts,
                                                   unsigned* __restrict__ bucket,
                                                   unsigned* __restrict__ ovf,
                                                   unsigned* __restrict__ ovf_cnt) {
    __shared__ float sm[6];
    reduce_keys64(pb, sm);
    const float mnx = sm[0], mny = sm[1], mnz = sm[2];
    const float mxx = sm[3], mxy = sm[4], mxz = sm[5];
    int q = blockIdx.x * blockDim.x + threadIdx.x;
    int i0 = q * 4;
    if (i0 >= n) return;
    float ax[4], ay[4], az[4];
    int cnt4 = 4;
    if (i0 + 4 <= n) {
        const float4* p4 = (const float4*)(xyz + (size_t)i0 * 3);
        float4 v0 = p4[0], v1 = p4[1], v2 = p4[2];
        ax[0]=v0.x; ax[1]=v0.w; ax[2]=v1.z; ax[3]=v2.y;
        ay[0]=v0.y; ay[1]=v1.x; ay[2]=v1.w; ay[3]=v2.z;
        az[0]=v0.z; az[1]=v1.y; az[2]=v2.x; az[3]=v2.w;
    } else {
        cnt4 = n - i0;
        for (int k = 0; k < cnt4; k++) {
            ax[k] = xyz[3 * (i0 + k)]; ay[k] = xyz[3 * (i0 + k) + 1]; az[k] = xyz[3 * (i0 + k) + 2];
        }
    }
    #pragma unroll
    for (int k = 0; k < 4; k++) {
        if (k >= cnt4) break;
        if (ax[k] == 0.f || ay[k] == 0.f || az[k] == 0.f) continue;
        // exact op-order of reference: (x - min) / (max - min) * 47, f32, trunc
        int cx = (int)((ax[k] - mnx) / (mxx - mnx) * 47.0f);
        int cy = (int)((ay[k] - mny) / (mxy - mny) * 47.0f);
        int cz = (int)((az[k] - mnz) / (mxz - mnz) * 47.0f);
        unsigned cell = (unsigned)((cz * VOL + cy) * VOL + cx);
        unsigned slot = atomicAdd(&counts[cell], 1u);
        if (slot < CAP) {
            bucket[(size_t)cell * CAP + slot] = (unsigned)(i0 + k);
        } else {
            unsigned j = atomicAdd(ovf_cnt, 1u);
            if (j < OVCAP) { ovf[2 * j] = cell; ovf[2 * j + 1] = (unsigned)(i0 + k); }
        }
    }
}

// ---- K3: accum; 512 threads = 8 waves, ONE cell per wave (r11 parallelism),
//      8 consecutive cells per block -> 32B-contiguous plane writes ----
__global__ __launch_bounds__(ACB) void vox_accum8(const unsigned* __restrict__ bucket,
                                                  const unsigned* __restrict__ counts,
                                                  const unsigned* __restrict__ ovf,
                                                  const unsigned* __restrict__ ovf_cnt,
                                                  const float* __restrict__ feat,
                                                  float* __restrict__ center) {
    __shared__ float tile[CPB8][FEATD];
    const int wave = threadIdx.x >> 6;              // 0..7
    const int lane = threadIdx.x & 63;
    const int base = blockIdx.x * CPB8;             // grid.x = VOL3/8
    const int cell = base + wave;
    const int f = lane % FEATD;                     // 0..18
    const int j = lane / FEATD;                     // 0..3 (j==3: idle lanes)
    const bool act = j < 3;

    unsigned cnt = counts[cell];
    unsigned use = cnt < CAP ? cnt : CAP;
    const unsigned* b = bucket + (size_t)cell * CAP;
    float acc = 0.f;
    // software-pipelined: 6 atoms/round (2 per j-group), indices one round ahead
    unsigned idx0 = 0, idx1 = 0;
    bool l0 = act && ((unsigned)j < use);
    bool l1 = act && ((unsigned)(j + 3) < use);
    if (l0) idx0 = b[j];
    if (l1) idx1 = b[j + 3];
    unsigned k = 0;
    while (k < use) {
        unsigned nk = k + 6;
        bool n0 = act && (nk + j < use);
        bool n1 = act && (nk + j + 3 < use);
        unsigned nidx0 = 0, nidx1 = 0;
        if (n0) nidx0 = b[nk + j];
        if (n1) nidx1 = b[nk + j + 3];
        if (l0) acc += feat[(size_t)idx0 * FEATD + f];   // 19 lanes span one row
        if (l1) acc += feat[(size_t)idx1 * FEATD + f];
        k = nk; idx0 = nidx0; idx1 = nidx1; l0 = n0; l1 = n1;
    }
    if (cnt > CAP) {   // cold overflow merge (never taken for this data)
        unsigned no = *ovf_cnt; if (no > OVCAP) no = OVCAP;
        if (lane < FEATD) {
            for (unsigned i = 0; i < no; i++)
                if (ovf[2 * i] == (unsigned)cell)
                    acc += feat[(size_t)ovf[2 * i + 1] * FEATD + f];
        }
    }
    // reduce the 3 j-partials into lanes 0..18
    float a1 = __shfl(acc, lane + FEATD, 64);
    float a2 = __shfl(acc, lane + 2 * FEATD, 64);
    if (lane < FEATD) tile[wave][lane] = acc + a1 + a2;
    __syncthreads();
    // coalesced write: 8 consecutive cells per feature plane = 32B burst
    int t = threadIdx.x;
    if (t < CPB8 * FEATD) {                          // 152 threads
        int ff = t >> 3, c = t & 7;                  // t/8, t%8
        center[(size_t)ff * VOL3 + base + c] = tile[c][ff];
    }
}

// ---- K4: 3x3x3 box conv; thread computes a 4x4 (x,z) tile via float4 rows ----
constexpr int XQ = VOL / 4;     // 12 x-quads
constexpr int CZB = VOL / 4;    // 12 z-blocks (4 z per thread)
constexpr int NCONV2 = FEATD * CZB * VOL * XQ;   // 131328 threads

__global__ __launch_bounds__(SCB) void vox_conv2(const float* __restrict__ center,
                                                 float* __restrict__ out) {
    int idx = blockIdx.x * blockDim.x + threadIdx.x;
    if (idx >= NCONV2) return;
    int xq = idx % XQ;
    int t = idx / XQ;
    int y = t % VOL;  t /= VOL;
    int zb = t % CZB;
    int f = t / CZB;
    const int x0 = xq * 4;
    const float* cf = center + (size_t)f * VOL3;

    const int ylo = (y > 0) ? y - 1 : 0, yhi = (y < VOL - 1) ? y + 1 : VOL - 1;

    auto rowsum4 = [&](const float* row) -> float4 {
        float4 a = *(const float4*)(row + x0);
        float m = (x0 > 0) ? row[x0 - 1] : 0.f;
        float p = (x0 + 4 < VOL) ? row[x0 + 4] : 0.f;
        return make_float4(m + a.x + a.y,
                           a.x + a.y + a.z,
                           a.y + a.z + a.w,
                           a.z + a.w + p);
    };
    auto psum = [&](int zz) -> float4 {
        float4 s = make_float4(0.f, 0.f, 0.f, 0.f);
        if ((unsigned)zz >= (unsigned)VOL) return s;
        for (int yy = ylo; yy <= yhi; yy++) {
            float4 r = rowsum4(cf + (zz * VOL + yy) * VOL);
            s.x += r.x; s.y += r.y; s.z += r.z; s.w += r.w;
        }
        return s;
    };

    const int z0 = zb * 4;
    float4 Pm = psum(z0 - 1), Pc = psum(z0);
    #pragma unroll
    for (int k = 0; k < 4; k++) {
        float4 Pn = psum(z0 + k + 1);
        float4 o = make_float4(Pm.x + Pc.x + Pn.x, Pm.y + Pc.y + Pn.y,
                               Pm.z + Pc.z + Pn.z, Pm.w + Pc.w + Pn.w);
        *(float4*)(out + (((size_t)f * VOL + (z0 + k)) * VOL + y) * VOL + x0) = o;
        Pm = Pc; Pc = Pn;
    }
}

extern "C" void kernel_launch(void* const* d_in, const int* in_sizes, int n_in,
                              void* d_out, int out_size, void* d_ws, size_t ws_size,
                              hipStream_t stream) {
    const float* xyz  = (const float*)d_in[0];
    const float* feat = (const float*)d_in[1];
    float* out = (float*)d_out;
    int n = in_sizes[0] / 3;

    char* w = (char*)d_ws;
    unsigned* pb      = (unsigned*)w;                        // NMB*6 u32 = 1536 B
    unsigned* ovf_cnt = (unsigned*)(w + 1536);               // 4 B (pad to 2048)
    unsigned* counts  = (unsigned*)(w + 2048);               // VOL3*4 = 442368
    size_t o3 = 2048 + (size_t)VOL3 * 4;                     // 444416 (256-aligned)
    unsigned* bucket  = (unsigned*)(w + o3);                 // VOL3*CAP*4 = 56.6 MB
    size_t o4 = o3 + (size_t)VOL3 * CAP * 4;
    float* center     = (float*)(w + o4);                    // FEATD*VOL3*4 = 8.4 MB
    size_t o5 = o4 + (size_t)FEATD * VOL3 * 4;
    unsigned* ovf     = (unsigned*)(w + o5);                 // 2*OVCAP*4 = 64 KB
    size_t need = o5 + (size_t)2 * OVCAP * 4;

    if (ws_size < need) return;   // harness ws is ~256MB; never taken

    int nq = (n + 3) / 4;
    vox_minmax_p<<<NMB, 1024, 0, stream>>>(xyz, n, pb, counts, ovf_cnt);
    vox_scatter<<<(nq + SCB - 1) / SCB, SCB, 0, stream>>>(xyz, n, pb, counts, bucket, ovf, ovf_cnt);
    vox_accum8<<<NAB, ACB, 0, stream>>>(bucket, counts, ovf, ovf_cnt, feat, center);
    vox_conv2<<<(NCONV2 + SCB - 1) / SCB, SCB, 0, stream>>>(center, out);
}